// Round 4
// baseline (592.439 us; speedup 1.0000x reference)
//
#include <hip/hip_runtime.h>
#include <math.h>

// Problem constants
#define DIMS   6
#define NGEO   20
#define NPHI   27
#define NEXPERT 540
#define MPTS   256
#define NTEST  1024
#define NMAT   560          // experts + baselines
#define JIT    1e-4f
#define USTRIDE 33280       // packed padded upper-triangular floats per matrix
#define L2E    1.44269504088896340736f

// Row j of U (cols j..255) starts at uoff(j); each row padded to 4-float multiple.
__device__ __forceinline__ int uoff(int j){
    int m = j >> 2, r = j & 3;
    return 1024*m - 8*m*(m-1) + r*(256 - 4*m);
}

// Scalar-path loads: one panel row (32 floats) into SGPRs.
typedef __attribute__((ext_vector_type(16))) float sf16;
__device__ __forceinline__ void bload(const float* p, sf16& a, sf16& b){
    asm volatile("s_load_dwordx16 %0, %2, 0\n\t"
                 "s_load_dwordx16 %1, %2, 64"
                 : "=s"(a), "=s"(b) : "s"(p));
}
__device__ __forceinline__ void bwait(sf16& a, sf16& b){
    // ties the wait to the data so uses can't be scheduled before it
    asm volatile("s_waitcnt lgkmcnt(0)" : "+s"(a), "+s"(b));
}

// ---------------------------------------------------------------------------
// Kernel 1: 2-level GMM hard routing (fp64 to match np reference argmax)
// ---------------------------------------------------------------------------
__global__ __launch_bounds__(256)
void route_kernel(const float* __restrict__ Xt, const float* __restrict__ sm,
                  const float* __restrict__ ss,
                  const float* __restrict__ gm, const float* __restrict__ glv,
                  const float* __restrict__ glw,
                  const float* __restrict__ pm, const float* __restrict__ plv,
                  const float* __restrict__ plw,
                  int* __restrict__ e_idx, int* __restrict__ g_idx)
{
    int n = blockIdx.x*256 + threadIdx.x;
    if (n >= NTEST) return;
    double xs[DIMS];
    #pragma unroll
    for (int d=0; d<DIMS; d++)
        xs[d] = ((double)Xt[n*DIMS+d] - (double)sm[d]) / (double)ss[d];
    const double cst = (double)DIMS * 1.8378770664093453;  // D*log(2*pi)

    int bg = 0; double best = -1e300;
    for (int j=0; j<NGEO; j++){
        double s = 0.0;
        #pragma unroll
        for (int d=0; d<DIMS; d++){
            double lv = (double)glv[j*DIMS+d];
            double df = xs[d] - (double)gm[j*DIMS+d];
            s += lv + df*df*exp(-lv);
        }
        double lp = (double)glw[j] - 0.5*(s + cst);
        if (lp > best){ best = lp; bg = j; }
    }
    int bk = 0; best = -1e300;
    for (int k=0; k<NPHI; k++){
        double s = 0.0;
        int o = (bg*NPHI + k)*DIMS;
        #pragma unroll
        for (int d=0; d<DIMS; d++){
            double lv = (double)plv[o+d];
            double df = xs[d] - (double)pm[o+d];
            s += lv + df*df*exp(-lv);
        }
        double lp = (double)plw[bg*NPHI+k] - 0.5*(s + cst);
        if (lp > best){ best = lp; bk = k; }
    }
    e_idx[n] = bg*NPHI + bk;
    g_idx[n] = bg;
}

// ---------------------------------------------------------------------------
// Kernel 2: left-looking Cholesky, column-per-thread in registers.
// Update loop: wave-uniform B block via SCALAR loads (s_load_dwordx16 ->
// v_fma with SGPR operand, zero DS traffic), private a[m] via coalesced
// vector loads (L2-hot). Chunk swizzle (wave+block)&3 keeps idle chunks
// wave-uniform (execz skip) and balances heavy chunks across SIMDs/blocks.
// s_dcache_inv once per panel guards K$ lines spanning panel boundaries.
// ---------------------------------------------------------------------------
__global__ __launch_bounds__(256, 3)
void chol_kernel(const float* __restrict__ X_exp, const float* __restrict__ Y_exp,
                 const float* __restrict__ X_base, const float* __restrict__ Y_base,
                 const float* __restrict__ lls_e, const float* __restrict__ los_e,
                 const float* __restrict__ lno_e,
                 const float* __restrict__ lls_b, const float* __restrict__ los_b,
                 const float* __restrict__ lno_b,
                 float* __restrict__ Uws, float* __restrict__ Vws)
{
    __shared__ __align__(16) float Xs[256*8];    // 8 KB train points, stride 8
    __shared__ float Dl[32*36];                  // diag block of L (row l, col k)
    __shared__ float Dinv[32];                   // 1/diag(L)

    int b = blockIdx.x, t = threadIdx.x;
    int w = t >> 6, lane = t & 63;
    int q = (w + b) & 3;                         // column chunk for this wave
    int c = 64*q + lane;                         // owned column

    const float *Xtr, *Ytr;
    float lls, los, lno;
    if (b < NEXPERT){
        Xtr = X_exp + b*(MPTS*DIMS); Ytr = Y_exp + b*MPTS;
        lls = lls_e[b]; los = los_e[b]; lno = lno_e[b];
    } else {
        int g = b - NEXPERT;
        Xtr = X_base + g*(MPTS*DIMS); Ytr = Y_base + g*MPTS;
        lls = lls_b[g]; los = los_b[g]; lno = lno_b[g];
    }
    float ls2 = expf(2.f*lls);
    float os  = expf(los);
    float nv  = expf(lno) + JIT;
    float c1  = -0.5f*L2E/ls2;
    float* Ug = Uws + (size_t)b*USTRIDE;

    // stage X into LDS (padded stride 8; slots 6,7 never read)
    for (int i=t; i<MPTS*DIMS; i+=256){ int r=i/DIMS, d=i-r*DIMS; Xs[r*8+d]=Xtr[i]; }

    for (int j=0; j<8; j++){
        __syncthreads();                 // prev stores L2-visible; Dl free
        int l = c - 32*j;                // diag-local index of owned column
        bool act = (l >= 0);
        // whole-chunk skip is wave-uniform; inv only if this wave will s_load
        if (j > 0 && 64*q + 63 >= 32*j)
            asm volatile("s_dcache_inv" ::: "memory");

        float x[32];                     // x[k] = U[32j+k][c]
        if (act){
            // ---- build original K entries for this column ----
            float4 xa = *(const float4*)&Xs[c*8];
            float2 xb = *(const float2*)&Xs[c*8+4];
            #pragma unroll
            for (int k=0; k<32; k++){
                const float* Xr = &Xs[(32*j+k)*8];
                float4 ra = *(const float4*)Xr;
                float2 rb = *(const float2*)(Xr+4);
                float d0=xa.x-ra.x, d1=xa.y-ra.y, d2v=xa.z-ra.z, d3=xa.w-ra.w;
                float d4=xb.x-rb.x, d5=xb.y-rb.y;
                float dd = d0*d0+d1*d1+d2v*d2v+d3*d3+d4*d4+d5*d5;
                float val = os*exp2f(c1*dd);
                if (k == l) val += nv;   // diagonal
                x[k] = val;
            }
            // ---- subtract previous panels: scalar B, vector a ----
            for (int i2=0; i2<j; i2++){
                #pragma unroll
                for (int mh=0; mh<2; mh++){
                    float a[16];
                    #pragma unroll
                    for (int m=0; m<16; m++){
                        int ri = 32*i2 + 16*mh + m;
                        a[m] = Ug[uoff(ri) + 32*j + l - ri];   // U[ri][c]
                    }
                    #pragma unroll
                    for (int m=0; m<16; m++){
                        int ri = 32*i2 + 16*mh + m;
                        const float* rp = Ug + (uoff(ri) + 32*j - ri);
                        sf16 b0, b1;
                        bload(rp, b0, b1);
                        bwait(b0, b1);
                        float nam = -a[m];
                        #pragma unroll
                        for (int k=0; k<16; k++) x[k]    = fmaf(b0[k], nam, x[k]);
                        #pragma unroll
                        for (int k=0; k<16; k++) x[16+k] = fmaf(b1[k], nam, x[16+k]);
                    }
                }
            }
        }
        // ---- diag 32x32 factor: owning half-wave, shfl only ----
        if (l >= 0 && l < 32){
            int lb = 32*(j & 1);          // lane base of the diag group
            float r[32];
            #pragma unroll
            for (int k=0; k<32; k++) r[k] = (k <= l) ? x[k] : 0.f;
            float myinv = 1.f;
            #pragma unroll
            for (int cc=0; cc<32; cc++){
                float pivsq = __shfl(r[cc], lb + cc);
                float inv = rsqrtf(pivsq);
                r[cc] *= inv;
                if (l == cc) myinv = inv;
                #pragma unroll
                for (int k=cc+1; k<32; k++) r[k] -= r[cc]*__shfl(r[cc], lb + k);
            }
            Dinv[l] = myinv;
            #pragma unroll
            for (int k=0; k<32; k++){
                if (k <= l) Dl[l*36 + k] = r[k];
                x[k] = r[k];
            }
        }
        __syncthreads();                  // Dl/Dinv visible
        // ---- trsm: in-thread, D via LDS broadcast ----
        if (l >= 32){
            #pragma unroll
            for (int cc=0; cc<32; cc++){
                float a = x[cc]*Dinv[cc];
                x[cc] = a;
                #pragma unroll
                for (int k=cc+1; k<32; k++)
                    x[k] -= Dl[k*36 + cc]*a;
            }
        }
        // ---- store panel column to global (once) ----
        if (act){
            #pragma unroll
            for (int k=0; k<32; k++){
                if (l >= k) Ug[uoff(32*j+k) + l - k] = x[k];
            }
        }
    }
    __syncthreads();

    // v = L^-1 y  (forward solve, wave 0 only; L columns = U rows, coalesced)
    if (t < 64){
        int l = t;
        float z[4], rd[4];
        #pragma unroll
        for (int qq2=0; qq2<4; qq2++){
            z[qq2]  = Ytr[64*qq2 + l];
            rd[qq2] = 1.f/Ug[uoff(64*qq2 + l)];
        }
        int offj = 0;
        #pragma unroll
        for (int qq2=0; qq2<4; qq2++){
            for (int j2=0; j2<64; j2++){
                int j = 64*qq2 + j2;
                float zf = __shfl(z[qq2], j2) * __shfl(rd[qq2], j2);
                if (l == j2) z[qq2] = zf;
                #pragma unroll
                for (int r=qq2; r<4; r++){
                    int dd = 64*(r-qq2) + (l - j2);
                    int dc = dd > 0 ? dd : 0;
                    float uv = Ug[offj + dc];
                    if (dd > 0) z[r] -= uv*zf;
                }
                offj += (259-j)&~3;
            }
        }
        #pragma unroll
        for (int qq2=0; qq2<4; qq2++) Vws[b*256 + 64*qq2 + l] = z[qq2];
    }
}

// ---------------------------------------------------------------------------
// Kernel 3: per-point prediction (one wave per (point, side)) + rBCM combine
// ---------------------------------------------------------------------------
__global__ __launch_bounds__(256)
void predict_kernel(const float* __restrict__ Xt,
                    const float* __restrict__ X_exp, const float* __restrict__ X_base,
                    const float* __restrict__ lls_e, const float* __restrict__ los_e,
                    const float* __restrict__ lno_e,
                    const float* __restrict__ lls_b, const float* __restrict__ los_b,
                    const float* __restrict__ lno_b,
                    const int* __restrict__ nullmask,
                    const float* __restrict__ Uws, const float* __restrict__ Vws,
                    const int* __restrict__ e_idx, const int* __restrict__ g_idx,
                    float* __restrict__ out)
{
    __shared__ float res[4][4];   // per local wave: mu, var, prior
    int lw = threadIdx.x >> 6, l = threadIdx.x & 63;
    int wt = blockIdx.x*4 + lw, n = wt >> 1, side = wt & 1;

    int bidx; const float* Xtr; float lls, los, lno;
    if (side == 0){
        int ee = e_idx[n]; bidx = ee; Xtr = X_exp + ee*(MPTS*DIMS);
        lls = lls_e[ee]; los = los_e[ee]; lno = lno_e[ee];
    } else {
        int g = g_idx[n]; bidx = NEXPERT + g; Xtr = X_base + g*(MPTS*DIMS);
        lls = lls_b[g]; los = los_b[g]; lno = lno_b[g];
    }
    float ls2 = expf(2.f*lls), os = expf(los), nv = expf(lno) + JIT;
    float c1 = -0.5f*L2E/ls2;
    float xt[DIMS];
    #pragma unroll
    for (int d=0; d<DIMS; d++) xt[d] = Xt[n*DIMS + d];

    const float* Ug = Uws + (size_t)bidx*USTRIDE;
    const float* vv = Vws + bidx*256;

    // k* into registers (rows 64q+l), plus diag reciprocals
    float z[4], rd[4];
    #pragma unroll
    for (int q=0; q<4; q++){
        int m = 64*q + l;
        float d2 = 0.f;
        #pragma unroll
        for (int d=0; d<DIMS; d++){ float df = xt[d]-Xtr[m*DIMS+d]; d2 += df*df; }
        z[q]  = os*exp2f(c1*d2);
        rd[q] = 1.f/Ug[uoff(m)];
    }
    // w = L^-1 k*  (forward solve; L columns = U rows, coalesced loads)
    int offj = 0;
    #pragma unroll
    for (int q=0; q<4; q++){
        #pragma unroll 4
        for (int j2=0; j2<64; j2++){
            int j = 64*q + j2;
            float zf = __shfl(z[q], j2) * __shfl(rd[q], j2);
            if (l == j2) z[q] = zf;
            #pragma unroll
            for (int r=q; r<4; r++){
                int dd = 64*(r-q) + (l - j2);
                int dc = dd > 0 ? dd : 0;
                float uv = Ug[offj + dc];
                if (dd > 0) z[r] -= uv*zf;
            }
            offj += (259-j)&~3;
        }
    }
    // q = w.w ; mu = w.v
    float qq = 0.f, mu = 0.f;
    #pragma unroll
    for (int q=0; q<4; q++){ qq += z[q]*z[q]; mu += z[q]*vv[64*q + l]; }
    #pragma unroll
    for (int o=32; o>0; o>>=1){ qq += __shfl_xor(qq, o); mu += __shfl_xor(mu, o); }
    if (l == 0){
        res[lw][0] = mu;
        res[lw][1] = fmaxf(os - qq, JIT) + nv;   // predictive var incl noise
        res[lw][2] = os + nv;                    // prior
    }
    __syncthreads();
    if (threadIdx.x < 2){
        int pp = threadIdx.x, n2 = blockIdx.x*2 + pp;
        float mu_e = res[2*pp][0],   var_e = res[2*pp][1],   pr_e = res[2*pp][2];
        float mu_b = res[2*pp+1][0], var_b = res[2*pp+1][1], pr_b = res[2*pp+1][2];
        int ee = e_idx[n2];
        float be = (nullmask[ee] == 0) ? 0.f
                 : fmaxf(0.5f*(logf(pr_e) - logf(var_e)), 0.f);
        float bb = fmaxf(0.5f*(logf(pr_b) - logf(var_b)), 0.f);
        float prec = be/var_e + bb/var_b + (1.f - be - bb)/pr_b;
        prec = fmaxf(prec, 1e-6f);
        out[n2]        = (be*mu_e/var_e + bb*mu_b/var_b)/prec;
        out[NTEST + n2] = 1.f/prec;
    }
}

// ---------------------------------------------------------------------------
extern "C" void kernel_launch(void* const* d_in, const int* in_sizes, int n_in,
                              void* d_out, int out_size, void* d_ws, size_t ws_size,
                              hipStream_t stream)
{
    const float* X_test  = (const float*)d_in[0];
    const float* X_exp   = (const float*)d_in[1];
    const float* Y_exp   = (const float*)d_in[2];
    const float* X_base  = (const float*)d_in[3];
    const float* Y_base  = (const float*)d_in[4];
    const float* lls_e   = (const float*)d_in[5];
    const float* los_e   = (const float*)d_in[6];
    const float* lno_e   = (const float*)d_in[7];
    const float* lls_b   = (const float*)d_in[8];
    const float* los_b   = (const float*)d_in[9];
    const float* lno_b   = (const float*)d_in[10];
    const float* sm      = (const float*)d_in[11];
    const float* ss      = (const float*)d_in[12];
    const float* gm      = (const float*)d_in[13];
    const float* glv     = (const float*)d_in[14];
    const float* glw     = (const float*)d_in[15];
    const float* pm      = (const float*)d_in[16];
    const float* plv     = (const float*)d_in[17];
    const float* plw     = (const float*)d_in[18];
    const int*   nmask   = (const int*)d_in[19];

    float* Uws = (float*)d_ws;                       // NMAT*USTRIDE floats (74.5 MB)
    float* Vws = Uws + (size_t)NMAT*USTRIDE;         // NMAT*256 floats
    int*   e_idx = (int*)(Vws + (size_t)NMAT*256);   // NTEST ints
    int*   g_idx = e_idx + NTEST;                    // NTEST ints
    float* out = (float*)d_out;

    route_kernel<<<dim3(NTEST/256), dim3(256), 0, stream>>>(
        X_test, sm, ss, gm, glv, glw, pm, plv, plw, e_idx, g_idx);
    chol_kernel<<<dim3(NMAT), dim3(256), 0, stream>>>(
        X_exp, Y_exp, X_base, Y_base,
        lls_e, los_e, lno_e, lls_b, los_b, lno_b, Uws, Vws);
    predict_kernel<<<dim3(NTEST/2), dim3(256), 0, stream>>>(
        X_test, X_exp, X_base,
        lls_e, los_e, lno_e, lls_b, los_b, lno_b,
        nmask, Uws, Vws, e_idx, g_idx, out);
}